// Round 1
// baseline (3070.983 us; speedup 1.0000x reference)
//
#include <hip/hip_runtime.h>

#define STYLE_EPS 1e-4f

// ---------------------------------------------------------------- reductions
__device__ __forceinline__ float block_reduce_sum(float v) {
  __shared__ float ws[8];
  #pragma unroll
  for (int off = 32; off > 0; off >>= 1) v += __shfl_down(v, off, 64);
  __syncthreads();                       // protect ws across repeated calls
  int lane = threadIdx.x & 63, wid = threadIdx.x >> 6;
  if (lane == 0) ws[wid] = v;
  __syncthreads();
  float s = 0.f;
  int nw = (blockDim.x + 63) >> 6;
  for (int i = 0; i < nw; ++i) s += ws[i];
  return s;
}

// out[row] = mean(in[row][0..K)) ; grid = nrows, block = 256
__global__ void row_mean_kernel(const float* __restrict__ in, float* __restrict__ out, int K) {
  size_t row = blockIdx.x;
  const float4* p4 = (const float4*)(in + row * (size_t)K);
  int K4 = K >> 2;
  float s = 0.f;
  for (int i = threadIdx.x; i < K4; i += blockDim.x) {
    float4 v = p4[i];
    s += (v.x + v.y) + (v.z + v.w);
  }
  s = block_reduce_sum(s);
  if (threadIdx.x == 0) out[row] = s / (float)K;
}

// ------------------------------------------------------- symmetric Gram (fp32)
// srm[b] += X_tile_i @ X_tile_j^T over one K chunk.
// grid: (nchunks, 3 tile-pairs {(0,0),(0,1),(1,1)}, nbatch); block 256.
// 128x128 tile, 8x8 micro-tile, Kt=32, k-major LDS, fp32 atomic accumulate.
__global__ void gram_kernel(const float* __restrict__ X, float* __restrict__ srm,
                            int K, int kchunk) {
  __shared__ float As[32][128];
  __shared__ float Bs[32][128];
  const int pair = blockIdx.y;
  const int ti = (pair == 2) ? 1 : 0;
  const int tj = (pair == 0) ? 0 : 1;
  const int b = blockIdx.z;
  const float* __restrict__ Xb = X + (size_t)b * 256 * (size_t)K;
  const float* __restrict__ Ab = Xb + (size_t)(ti * 128) * (size_t)K;
  const float* __restrict__ Bb = Xb + (size_t)(tj * 128) * (size_t)K;
  const int k0 = blockIdx.x * kchunk;
  const int t = threadIdx.x;
  const int tx = t & 15, ty = t >> 4;
  const int lrow = t >> 1;          // 0..127
  const int lk = (t & 1) * 16;      // 0 or 16

  float acc[8][8];
  #pragma unroll
  for (int i = 0; i < 8; ++i)
    #pragma unroll
    for (int j = 0; j < 8; ++j) acc[i][j] = 0.f;

  const float* pa = Ab + (size_t)lrow * K + k0 + lk;
  const float* pb = Bb + (size_t)lrow * K + k0 + lk;

  for (int kk = 0; kk < kchunk; kk += 32) {
    float4 a0 = *(const float4*)(pa + kk);
    float4 a1 = *(const float4*)(pa + kk + 4);
    float4 a2 = *(const float4*)(pa + kk + 8);
    float4 a3 = *(const float4*)(pa + kk + 12);
    float4 c0 = *(const float4*)(pb + kk);
    float4 c1 = *(const float4*)(pb + kk + 4);
    float4 c2 = *(const float4*)(pb + kk + 8);
    float4 c3 = *(const float4*)(pb + kk + 12);
    __syncthreads();
    As[lk+ 0][lrow]=a0.x; As[lk+ 1][lrow]=a0.y; As[lk+ 2][lrow]=a0.z; As[lk+ 3][lrow]=a0.w;
    As[lk+ 4][lrow]=a1.x; As[lk+ 5][lrow]=a1.y; As[lk+ 6][lrow]=a1.z; As[lk+ 7][lrow]=a1.w;
    As[lk+ 8][lrow]=a2.x; As[lk+ 9][lrow]=a2.y; As[lk+10][lrow]=a2.z; As[lk+11][lrow]=a2.w;
    As[lk+12][lrow]=a3.x; As[lk+13][lrow]=a3.y; As[lk+14][lrow]=a3.z; As[lk+15][lrow]=a3.w;
    Bs[lk+ 0][lrow]=c0.x; Bs[lk+ 1][lrow]=c0.y; Bs[lk+ 2][lrow]=c0.z; Bs[lk+ 3][lrow]=c0.w;
    Bs[lk+ 4][lrow]=c1.x; Bs[lk+ 5][lrow]=c1.y; Bs[lk+ 6][lrow]=c1.z; Bs[lk+ 7][lrow]=c1.w;
    Bs[lk+ 8][lrow]=c2.x; Bs[lk+ 9][lrow]=c2.y; Bs[lk+10][lrow]=c2.z; Bs[lk+11][lrow]=c2.w;
    Bs[lk+12][lrow]=c3.x; Bs[lk+13][lrow]=c3.y; Bs[lk+14][lrow]=c3.z; Bs[lk+15][lrow]=c3.w;
    __syncthreads();
    #pragma unroll 8
    for (int k = 0; k < 32; ++k) {
      float av[8], bv[8];
      *(float4*)&av[0] = *(const float4*)&As[k][ty * 8];
      *(float4*)&av[4] = *(const float4*)&As[k][ty * 8 + 4];
      *(float4*)&bv[0] = *(const float4*)&Bs[k][tx * 8];
      *(float4*)&bv[4] = *(const float4*)&Bs[k][tx * 8 + 4];
      #pragma unroll
      for (int i = 0; i < 8; ++i)
        #pragma unroll
        for (int j = 0; j < 8; ++j)
          acc[i][j] = fmaf(av[i], bv[j], acc[i][j]);
    }
  }
  float* dst = srm + ((size_t)b << 16);
  #pragma unroll
  for (int i = 0; i < 8; ++i) {
    int r = ti * 128 + ty * 8 + i;
    #pragma unroll
    for (int j = 0; j < 8; ++j) {
      int cc = tj * 128 + tx * 8 + j;
      atomicAdd(dst + (size_t)r * 256 + cc, acc[i][j]);
    }
  }
}

// cov = srm*inv_n - outer(mean,mean) + eps*I, mirroring the uncomputed (1,0) tile
__global__ void cov_finalize_kernel(const float* __restrict__ srm, const float* __restrict__ mean,
                                    float* __restrict__ cov, float inv_n, float eps) {
  int m = blockIdx.y;
  int idx = blockIdx.x * 256 + threadIdx.x;   // 0..65535
  int c = idx >> 8, d = idx & 255;
  size_t base = (size_t)m << 16;
  float s = ((c >> 7) > (d >> 7)) ? srm[base + ((size_t)d << 8) + c] : srm[base + idx];
  float v = s * inv_n - mean[m * 256 + c] * mean[m * 256 + d];
  if (c == d) v += eps;
  cov[base + idx] = v;
}

// sumsq[m] = ||A_m||_F^2 ; grid = nmat, block 256
__global__ void frob_kernel(const float* __restrict__ A, float* __restrict__ sumsq) {
  int m = blockIdx.x;
  const float4* p = (const float4*)(A + ((size_t)m << 16));
  float s = 0.f;
  for (int i = threadIdx.x; i < 16384; i += 256) {
    float4 v = p[i];
    s += v.x * v.x + v.y * v.y + v.z * v.z + v.w * v.w;
  }
  s = block_reduce_sum(s);
  if (threadIdx.x == 0) sumsq[m] = s;
}

// Y = A * rsqrt(sumsq) ; Z = I ; grid (256, nmat)
__global__ void ns_init_kernel(const float* __restrict__ A, const float* __restrict__ sumsq,
                               float* __restrict__ Y, float* __restrict__ Z) {
  int m = blockIdx.y;
  int idx = blockIdx.x * 256 + threadIdx.x;
  float rn = rsqrtf(sumsq[m]);
  size_t o = ((size_t)m << 16) + idx;
  int c = idx >> 8, d = idx & 255;
  Y[o] = A[o] * rn;
  Z[o] = (c == d) ? 1.f : 0.f;
}

// Out = Y * sumsq^(1/4)   (= y * sqrt(frob_norm)) ; grid (256, nmat)
__global__ void ns_final_kernel(const float* __restrict__ Y, const float* __restrict__ sumsq,
                                float* __restrict__ Out) {
  int m = blockIdx.y;
  float f = sqrtf(sqrtf(sumsq[m]));
  size_t o = ((size_t)m << 16) + blockIdx.x * 256 + threadIdx.x;
  Out[o] = Y[o] * f;
}

// ------------------------------------------------- 256x256x256 fp32 gemm tile
// C_tile = alpha*(A@B)_tile (+ diag_add on diagonal). 64x64 tile, 4x4 micro.
__device__ __forceinline__ void gemm64_tile(const float* __restrict__ A,
                                            const float* __restrict__ B,
                                            float* __restrict__ C,
                                            float alpha, float diag_add, int tile) {
  __shared__ float As[32][64];
  __shared__ float Bs[32][64];
  const int tm = tile >> 2, tn = tile & 3;
  const int t = threadIdx.x;
  const int tx = t & 15, ty = t >> 4;
  const int arow = t >> 2, akq = (t & 3) * 8;
  const int brow = t >> 3, bnq = (t & 7) * 8;
  float acc[4][4];
  #pragma unroll
  for (int i = 0; i < 4; ++i)
    #pragma unroll
    for (int j = 0; j < 4; ++j) acc[i][j] = 0.f;

  for (int kk = 0; kk < 256; kk += 32) {
    float4 a0 = *(const float4*)(A + (size_t)(tm * 64 + arow) * 256 + kk + akq);
    float4 a1 = *(const float4*)(A + (size_t)(tm * 64 + arow) * 256 + kk + akq + 4);
    float4 b0 = *(const float4*)(B + (size_t)(kk + brow) * 256 + tn * 64 + bnq);
    float4 b1 = *(const float4*)(B + (size_t)(kk + brow) * 256 + tn * 64 + bnq + 4);
    __syncthreads();
    As[akq + 0][arow] = a0.x; As[akq + 1][arow] = a0.y; As[akq + 2][arow] = a0.z; As[akq + 3][arow] = a0.w;
    As[akq + 4][arow] = a1.x; As[akq + 5][arow] = a1.y; As[akq + 6][arow] = a1.z; As[akq + 7][arow] = a1.w;
    *(float4*)&Bs[brow][bnq] = b0;
    *(float4*)&Bs[brow][bnq + 4] = b1;
    __syncthreads();
    #pragma unroll 8
    for (int k = 0; k < 32; ++k) {
      float4 av4 = *(const float4*)&As[k][ty * 4];
      float4 bv4 = *(const float4*)&Bs[k][tx * 4];
      float av[4] = {av4.x, av4.y, av4.z, av4.w};
      float bv[4] = {bv4.x, bv4.y, bv4.z, bv4.w};
      #pragma unroll
      for (int i = 0; i < 4; ++i)
        #pragma unroll
        for (int j = 0; j < 4; ++j)
          acc[i][j] = fmaf(av[i], bv[j], acc[i][j]);
    }
  }
  #pragma unroll
  for (int i = 0; i < 4; ++i) {
    int r = tm * 64 + ty * 4 + i;
    #pragma unroll
    for (int j = 0; j < 4; ++j) {
      int c = tn * 64 + tx * 4 + j;
      float v = alpha * acc[i][j];
      if (r == c) v += diag_add;
      C[(size_t)r * 256 + c] = v;
    }
  }
}

// T = 1.5*I - 0.5*(Z@Y) ; grid (16, nmat)
__global__ void ns_t_kernel(const float* __restrict__ Z, const float* __restrict__ Y,
                            float* __restrict__ T) {
  size_t o = (size_t)blockIdx.y << 16;
  gemm64_tile(Z + o, Y + o, T + o, -0.5f, 1.5f, blockIdx.x);
}

// Yn = Y@T (m < nmat) ; Zn = T@Z (m >= nmat) ; grid (16, 2*nmat)
__global__ void ns_yz_kernel(const float* __restrict__ Y, const float* __restrict__ Z,
                             const float* __restrict__ T,
                             float* __restrict__ Yn, float* __restrict__ Zn, int nmat) {
  int m = blockIdx.y;
  const float* Ap; const float* Bp; float* Cp;
  if (m < nmat) { size_t o = (size_t)m << 16; Ap = Y + o; Bp = T + o; Cp = Yn + o; }
  else          { size_t o = (size_t)(m - nmat) << 16; Ap = T + o; Bp = Z + o; Cp = Zn + o; }
  gemm64_tile(Ap, Bp, Cp, 1.f, 0.f, blockIdx.x);
}

// C[m] = A[m*sA] @ B[m*sB] ; grid (16, nmat)
__global__ void gemm_stride_kernel(const float* __restrict__ A, long sA,
                                   const float* __restrict__ B, long sB,
                                   float* __restrict__ C, long sC) {
  int m = blockIdx.y;
  gemm64_tile(A + (size_t)m * sA, B + (size_t)m * sB, C + (size_t)m * sC, 1.f, 0.f, blockIdx.x);
}

// out[0] = mean((meanB-meanT)^2) + mean(diag(covT + covB - 2*sqrtM)) ; 1 block
__global__ void loss_kernel(const float* __restrict__ meanB, const float* __restrict__ meanT,
                            const float* __restrict__ covT, const float* __restrict__ covB,
                            const float* __restrict__ sqrtM, float* __restrict__ out) {
  float s1 = 0.f, s2 = 0.f;
  for (int i = threadIdx.x; i < 2048; i += 256) {
    int b = i >> 8, c = i & 255;
    float dm = meanB[i] - meanT[c];
    s1 += dm * dm;
    size_t di = ((size_t)b << 16) + (size_t)c * 257;
    s2 += covT[(size_t)c * 257] + covB[di] - 2.f * sqrtM[di];
  }
  s1 = block_reduce_sum(s1);
  s2 = block_reduce_sum(s2);
  if (threadIdx.x == 0) out[0] = (s1 + s2) / 2048.f;
}

// ------------------------------------------------------------------- launch
extern "C" void kernel_launch(void* const* d_in, const int* in_sizes, int n_in,
                              void* d_out, int out_size, void* d_ws, size_t ws_size,
                              hipStream_t stream) {
  const float* x  = (const float*)d_in[0];   // [8,256,256,256]
  const float* tf = (const float*)d_in[1];   // [256,16384]
  float* out = (float*)d_out;
  float* W = (float*)d_ws;

  const size_t M = 65536;   // 256*256
  float* meanT = W;                       // 256
  float* meanB = meanT + 256;             // 2048
  float* srmT  = meanB + 2048;            // 65536
  float* covT  = srmT + M;                // 65536
  float* srmB  = covT + M;                // 8*65536
  float* covB  = srmB + 8 * M;            // 8*65536
  float* covTs = covB + 8 * M;            // 65536
  float* Ya    = covTs + M;               // 8*65536
  float* Yb    = Ya + 8 * M;
  float* Za    = Yb + 8 * M;
  float* Zb    = Za + 8 * M;
  float* Tm    = Zb + 8 * M;
  float* P1    = Tm + 8 * M;              // sandwich temp, later sqrtM
  float* Mm    = P1 + 8 * M;              // sandwich result
  float* sumsq = Mm + 8 * M;              // 16

  // zero the atomic accumulators (ws is poisoned 0xAA before every call)
  hipMemsetAsync(srmT, 0, M * sizeof(float), stream);
  hipMemsetAsync(srmB, 0, 8 * M * sizeof(float), stream);

  // ---- target branch ----
  row_mean_kernel<<<256, 256, 0, stream>>>(tf, meanT, 16384);
  gram_kernel<<<dim3(32, 3, 1), 256, 0, stream>>>(tf, srmT, 16384, 512);
  cov_finalize_kernel<<<dim3(256, 1), 256, 0, stream>>>(srmT, meanT, covT, 1.f / 16384.f, STYLE_EPS);

  // NS(covT), batch=1
  frob_kernel<<<1, 256, 0, stream>>>(covT, sumsq);
  ns_init_kernel<<<dim3(256, 1), 256, 0, stream>>>(covT, sumsq, Ya, Za);
  {
    float *y = Ya, *yn = Yb, *z = Za, *zn = Zb;
    for (int it = 0; it < 12; ++it) {
      ns_t_kernel<<<dim3(16, 1), 256, 0, stream>>>(z, y, Tm);
      ns_yz_kernel<<<dim3(16, 2), 256, 0, stream>>>(y, z, Tm, yn, zn, 1);
      float* tp;
      tp = y; y = yn; yn = tp;
      tp = z; z = zn; zn = tp;
    }
    ns_final_kernel<<<dim3(256, 1), 256, 0, stream>>>(y, sumsq, covTs);
  }

  // ---- batch branch ----
  row_mean_kernel<<<2048, 256, 0, stream>>>(x, meanB, 65536);
  gram_kernel<<<dim3(32, 3, 8), 256, 0, stream>>>(x, srmB, 65536, 2048);
  cov_finalize_kernel<<<dim3(256, 8), 256, 0, stream>>>(srmB, meanB, covB, 1.f / 65536.f, STYLE_EPS);

  // Mm = covTs @ covB @ covTs
  gemm_stride_kernel<<<dim3(16, 8), 256, 0, stream>>>(covTs, 0L, covB, (long)M, P1, (long)M);
  gemm_stride_kernel<<<dim3(16, 8), 256, 0, stream>>>(P1, (long)M, covTs, 0L, Mm, (long)M);

  // NS(Mm), batch=8
  frob_kernel<<<8, 256, 0, stream>>>(Mm, sumsq);
  ns_init_kernel<<<dim3(256, 8), 256, 0, stream>>>(Mm, sumsq, Ya, Za);
  {
    float *y = Ya, *yn = Yb, *z = Za, *zn = Zb;
    for (int it = 0; it < 12; ++it) {
      ns_t_kernel<<<dim3(16, 8), 256, 0, stream>>>(z, y, Tm);
      ns_yz_kernel<<<dim3(16, 16), 256, 0, stream>>>(y, z, Tm, yn, zn, 8);
      float* tp;
      tp = y; y = yn; yn = tp;
      tp = z; z = zn; zn = tp;
    }
    ns_final_kernel<<<dim3(256, 8), 256, 0, stream>>>(y, sumsq, P1);  // P1 := sqrt_term
  }

  // ---- loss ----
  loss_kernel<<<1, 256, 0, stream>>>(meanB, meanT, covT, covB, P1, out);
}